// Round 20
// baseline (431.516 us; speedup 1.0000x reference)
//
#include <hip/hip_runtime.h>
#include <stdint.h>

/* AdditiveAttention (B=4, Q=256, K=1024, D=512, H=256)
 * out[b,i,v] = sum_j softmax_j(sum_h tanh(q[b,i,h]+k[b,j,h])*wv[h]) * values[b,j,v],
 * masked to j < valid_lens[b].
 * R20: OUTPUT IS FLOAT32 (the session-long bug). The "(bf16" in the harness
 * error label is a hardcoded f-string literal, not the out dtype. All prior
 * rounds packed bf16 pairs into half of the f32 buffer -> deterministic
 * absmax 0.5888672 regardless of variant (and 2-byte diag writes landed in
 * f32 mantissas, invisibly). Inputs f32, valid_lens auto-decoded (i32 exact). */

#define NB 4
#define NQ 256
#define NK 1024
#define ND 512
#define NH 256
#define QT 4
#define RT 16

__device__ __forceinline__ float th(float x) {
  float e = __expf(2.0f * x);
  return 1.0f - 2.0f / (e + 1.0f);
}

/* 8-class valid_lens decode: {i32,i64,f32,f64,i16,f16,bf16,fallback}. */
__device__ void ff_vldec(const int* p, int* v) {
  bool ok = true;
  for (int i = 0; i < 4; ++i) { int x = p[i]; if (x < 1 || x > NK) ok = false; }
  if (ok) { for (int i = 0; i < 4; ++i) v[i] = p[i]; return; }
  ok = true;
  for (int i = 0; i < 4; ++i) {
    if (p[2 * i + 1] != 0) ok = false;
    int x = p[2 * i]; if (x < 1 || x > NK) ok = false;
  }
  if (ok) { for (int i = 0; i < 4; ++i) v[i] = p[2 * i]; return; }
  ok = true;
  for (int i = 0; i < 4; ++i) {
    union { int i; float f; } u; u.i = p[i];
    if (!(u.f >= 1.0f && u.f <= 1024.0f && u.f == floorf(u.f))) ok = false;
  }
  if (ok) {
    for (int i = 0; i < 4; ++i) { union { int i; float f; } u; u.i = p[i]; v[i] = (int)u.f; }
    return;
  }
  ok = true;
  for (int i = 0; i < 4; ++i) {
    union { long long l; double d; } u;
    u.l = ((long long)p[2 * i + 1] << 32) | (unsigned int)p[2 * i];
    if (!(u.d >= 1.0 && u.d <= 1024.0 && u.d == floor(u.d))) ok = false;
  }
  if (ok) {
    for (int i = 0; i < 4; ++i) {
      union { long long l; double d; } u;
      u.l = ((long long)p[2 * i + 1] << 32) | (unsigned int)p[2 * i];
      v[i] = (int)u.d;
    }
    return;
  }
  const uint16_t* hh = (const uint16_t*)p;
  const short*    s  = (const short*)p;
  ok = true;
  for (int i = 0; i < 4; ++i) { int x = s[i]; if (x < 1 || x > NK) ok = false; }
  if (ok) { for (int i = 0; i < 4; ++i) v[i] = s[i]; return; }
  ok = true;
  for (int i = 0; i < 4; ++i) {
    union { uint16_t u; _Float16 h; } u; u.u = hh[i];
    float f = (float)u.h;
    if (!(f >= 1.0f && f <= 1024.0f && f == floorf(f))) ok = false;
  }
  if (ok) {
    for (int i = 0; i < 4; ++i) {
      union { uint16_t u; _Float16 h; } u; u.u = hh[i];
      v[i] = (int)(float)u.h;
    }
    return;
  }
  ok = true;
  for (int i = 0; i < 4; ++i) {
    union { uint32_t u; float f; } u; u.u = ((uint32_t)hh[i]) << 16;
    if (!(u.f >= 1.0f && u.f <= 1028.0f)) ok = false;
  }
  if (ok) {
    for (int i = 0; i < 4; ++i) {
      union { uint32_t u; float f; } u; u.u = ((uint32_t)hh[i]) << 16;
      int x = (int)(u.f + 0.5f); if (x > NK) x = NK; v[i] = x;
    }
    return;
  }
  for (int i = 0; i < 4; ++i) v[i] = NK;  /* fail-safe: unmasked */
}

/* ff_projq: qp[b][r][h] = sum_d queries[b][r][d] * Wq[h][d] */
__global__ __launch_bounds__(256) void ff_projq(
    const float* __restrict__ in, const float* __restrict__ W,
    float* __restrict__ out)
{
  __shared__ float xs[RT * ND];
  const int t = threadIdx.x, r0 = blockIdx.x * RT, b = blockIdx.y;
  const float* src = in + ((size_t)b * NQ + r0) * ND;
  for (int i = t; i < RT * ND / 4; i += 256) {
    float4 u = ((const float4*)src)[i];
    float* d = &xs[i * 4];
    d[0] = u.x; d[1] = u.y; d[2] = u.z; d[3] = u.w;
  }
  __syncthreads();
  float acc[RT];
  for (int i = 0; i < RT; ++i) acc[i] = 0.0f;
  const float* wr = W + (size_t)t * ND;
  for (int c = 0; c < ND / 4; ++c) {
    float4 w = ((const float4*)wr)[c];
    for (int i = 0; i < RT; ++i) {
      const float* x = &xs[i * ND + c * 4];
      acc[i] += w.x * x[0] + w.y * x[1] + w.z * x[2] + w.w * x[3];
    }
  }
  float* o = out + ((size_t)b * NQ + r0) * NH + t;
  for (int i = 0; i < RT; ++i) o[i * NH] = acc[i];
}

/* ff_projk: kp[b][h][r] = sum_d keys[b][r][d] * Wk[h][d]  (transposed store) */
__global__ __launch_bounds__(256) void ff_projk(
    const float* __restrict__ in, const float* __restrict__ W,
    float* __restrict__ out)
{
  __shared__ float xs[RT * ND];
  const int t = threadIdx.x, r0 = blockIdx.x * RT, b = blockIdx.y;
  const float* src = in + ((size_t)b * NK + r0) * ND;
  for (int i = t; i < RT * ND / 4; i += 256) {
    float4 u = ((const float4*)src)[i];
    float* d = &xs[i * 4];
    d[0] = u.x; d[1] = u.y; d[2] = u.z; d[3] = u.w;
  }
  __syncthreads();
  float acc[RT];
  for (int i = 0; i < RT; ++i) acc[i] = 0.0f;
  const float* wr = W + (size_t)t * ND;
  for (int c = 0; c < ND / 4; ++c) {
    float4 w = ((const float4*)wr)[c];
    for (int i = 0; i < RT; ++i) {
      const float* x = &xs[i * ND + c * 4];
      acc[i] += w.x * x[0] + w.y * x[1] + w.z * x[2] + w.w * x[3];
    }
  }
  float* o = out + ((size_t)b * NH + t) * NK + r0;
  for (int i = 0; i < RT; i += 4)
    *(float4*)(o + i) = make_float4(acc[i], acc[i + 1], acc[i + 2], acc[i + 3]);
}

/* ff_attn: scores + masked softmax + PV.  F32 OUTPUT. */
__global__ __launch_bounds__(256) void ff_attn(
    const float* __restrict__ qp, const float* __restrict__ kp,
    const float* __restrict__ vals, const int* __restrict__ vlraw,
    const float* __restrict__ wvp, float* __restrict__ out)
{
  __shared__ float qs[QT * NH];
  __shared__ float ws[NH];
  __shared__ float ss[QT * NK];

  const int t  = threadIdx.x;
  const int q0 = blockIdx.x * QT;
  const int b  = blockIdx.y;

  const float* qsrc = qp + ((size_t)b * NQ + q0) * NH;
  for (int i = 0; i < QT; ++i) qs[t + 256 * i] = qsrc[t + 256 * i];
  ws[t] = wvp[t];
  __syncthreads();

  int vls[4];
  ff_vldec(vlraw, vls);
  const int vl = vls[b];

  const int kb = t * 4;
  float a0[QT], a1[QT], a2[QT], a3[QT];
  for (int i = 0; i < QT; ++i) { a0[i]=0.f; a1[i]=0.f; a2[i]=0.f; a3[i]=0.f; }
  const float* kpb = kp + (size_t)b * NH * NK;
  for (int h = 0; h < NH; ++h) {
    float4 kv = *(const float4*)(kpb + (size_t)h * NK + kb);
    float w = ws[h];
    for (int qi = 0; qi < QT; ++qi) {
      float qh = qs[qi * NH + h];
      a0[qi] += th(qh + kv.x) * w;
      a1[qi] += th(qh + kv.y) * w;
      a2[qi] += th(qh + kv.z) * w;
      a3[qi] += th(qh + kv.w) * w;
    }
  }

  for (int qi = 0; qi < QT; ++qi) {
    float4 s;
    s.x = (kb     < vl) ? a0[qi] : -1e6f;
    s.y = (kb + 1 < vl) ? a1[qi] : -1e6f;
    s.z = (kb + 2 < vl) ? a2[qi] : -1e6f;
    s.w = (kb + 3 < vl) ? a3[qi] : -1e6f;
    *(float4*)&ss[qi * NK + kb] = s;
  }
  __syncthreads();

  {
    const int wid = t >> 6, lane = t & 63;
    float* row = &ss[wid * NK];
    float pv[16];
    float m = -3.0e38f;
    for (int j = 0; j < 16; ++j) { pv[j] = row[lane + 64 * j]; m = fmaxf(m, pv[j]); }
    for (int o = 32; o >= 1; o >>= 1) m = fmaxf(m, __shfl_xor(m, o));
    float sum = 0.0f;
    for (int j = 0; j < 16; ++j) { pv[j] = __expf(pv[j] - m); sum += pv[j]; }
    for (int o = 32; o >= 1; o >>= 1) sum += __shfl_xor(sum, o);
    float r = 1.0f / sum;
    for (int j = 0; j < 16; ++j) row[lane + 64 * j] = pv[j] * r;
  }
  __syncthreads();

  float o0[QT], o1[QT];
  for (int i = 0; i < QT; ++i) { o0[i] = 0.0f; o1[i] = 0.0f; }
  const float* vb = vals + (size_t)b * NK * ND;
  for (int k = 0; k < NK; ++k) {
    float2 v2 = *(const float2*)(vb + (size_t)k * ND + 2 * t);
    for (int qi = 0; qi < QT; ++qi) {
      float a = ss[qi * NK + k];
      o0[qi] += a * v2.x;
      o1[qi] += a * v2.y;
    }
  }

  /* F32 stores: thread t owns columns 2t, 2t+1 of each of QT rows. */
  float* ob = out + ((size_t)b * NQ + q0) * ND;
  for (int qi = 0; qi < QT; ++qi)
    *(float2*)(ob + (size_t)qi * ND + 2 * t) = make_float2(o0[qi], o1[qi]);
}

extern "C" void kernel_launch(void* const* d_in, const int* in_sizes, int n_in,
                              void* d_out, int out_size, void* d_ws, size_t ws_size,
                              hipStream_t stream) {
  const float* queries = (const float*)d_in[0];
  const float* keys    = (const float*)d_in[1];
  const float* values  = (const float*)d_in[2];
  const int*   vlens   = (const int*)d_in[3];
  const float* Wq      = (const float*)d_in[4];
  const float* Wk      = (const float*)d_in[5];
  const float* wv      = (const float*)d_in[6];
  float* out = (float*)d_out;              /* F32 OUTPUT — the R20 fix */

  float* qp = (float*)d_ws;                 /* [B][Q][H]  1 MB */
  float* kp = qp + (size_t)NB * NQ * NH;    /* [B][H][K]  4 MB */

  ff_projq<<<dim3(NQ / RT, NB), 256, 0, stream>>>(queries, Wq, qp);
  ff_projk<<<dim3(NK / RT, NB), 256, 0, stream>>>(keys, Wk, kp);
  ff_attn<<<dim3(NQ / QT, NB), 256, 0, stream>>>(qp, kp, values, vlens, wv, out);
}